// Round 10
// baseline (368.766 us; speedup 1.0000x reference)
//
#include <hip/hip_runtime.h>
#include <hip/hip_bf16.h>

#define NN 50000
#define NE 800000
#define NB 512
#define HNN 25000          // nodes per half-slice
#define WT_S 136           // padded k-stride (bf16 elems) for transposed W
#define WT_M (128 * WT_S)  // elems per transposed weight matrix
#define DCAP 64            // padded CSR row capacity (deg ~ Poisson(16))

using u32 = unsigned int;
using u16 = unsigned short;
typedef __attribute__((ext_vector_type(8))) short short8;
typedef __attribute__((ext_vector_type(4))) float f32x4;

constexpr float BNS = 0.9999950000374998f;  // 1/sqrt(1+1e-5)

__device__ inline u16 f2bf(float f) {
    u32 b = __builtin_bit_cast(u32, f);
    return (u16)((b + 0x7FFFu + ((b >> 16) & 1u)) >> 16);
}
__device__ inline float bf2f(u32 u) {
    return __builtin_bit_cast(float, u << 16);
}
__device__ inline u32 pk2(float a, float b) {
    return (u32)f2bf(a) | ((u32)f2bf(b) << 16);
}

// sliced layouts: hbT[(fg*NN + node)*32 + (feat&31)], vnbT[(fg*NB + b)*32 + (feat&31)]

// ---------------- fused prep: wprep (blocks 0..447) + setup (blocks 448..703) ----------------
__global__ void k_prep(const float* __restrict__ nW, const float* __restrict__ cW1,
                       const float* __restrict__ cW2, u16* __restrict__ wt,
                       const float* __restrict__ vn_emb, float* __restrict__ vn,
                       u16* __restrict__ vnbT, const int* __restrict__ batch,
                       int* __restrict__ bstart, float* __restrict__ counts) {
    if (blockIdx.x < 448) {
        int idx = blockIdx.x * 256 + threadIdx.x;  // < 7*16384
        int m = idx >> 14, e = idx & 16383;
        int k = e >> 7, c = e & 127;
        const float* src = m == 0 ? nW : (m <= 3 ? cW1 + (m - 1) * 16384 : cW2 + (m - 4) * 16384);
        wt[m * WT_M + c * WT_S + k] = f2bf(src[e]);
        return;
    }
    int idx = (blockIdx.x - 448) * 256 + threadIdx.x;
    if (idx < NB * 128) {
        int b = idx >> 7, c = idx & 127;
        float v = vn_emb[c];
        vn[idx] = v;
        vnbT[((size_t)(c >> 5) * NB + b) * 32 + (c & 31)] = f2bf(v);
    }
    if (idx <= NB) {
        int b = idx;
        int lo = 0, hi = NN;
        while (lo < hi) { int m = (lo + hi) >> 1; if (batch[m] < b) lo = m + 1; else hi = m; }
        bstart[b] = lo;
        if (b < NB) {
            int b1 = b + 1, lo1 = 0, hi1 = NN;
            while (lo1 < hi1) { int m = (lo1 + hi1) >> 1; if (batch[m] < b1) lo1 = m + 1; else hi1 = m; }
            counts[b] = (float)(lo1 - lo);
        }
    }
}

// ---------------- padded CSR: one-pass scatter; entry = src | batch[src]<<16 ----------------
__global__ void k_pcsr(const int* __restrict__ ei, const int* __restrict__ batch,
                       int* __restrict__ deg, u32* __restrict__ nbr) {
    int e = blockIdx.x * 256 + threadIdx.x;
    if (e >= NE) return;
    int src = ei[e];
    int dst = ei[NE + e];
    int pos = atomicAdd(&deg[dst], 1);
    if (pos < DCAP) nbr[(size_t)dst * DCAP + pos] = (u32)src | ((u32)batch[src] << 16);
}

// ---------------- gather (XCD-pinned, feature-sliced inputs) ----------------
// slice s = bid&7: fgroup f = s&3 (features f*32..f*32+31), half hs = s>>2.
// 8 lanes/node: 4 flanes x 2 neighbor-pairs; shfl_xor(4) combine.
__global__ __launch_bounds__(256) void k_gather(
    const int* __restrict__ deg, const u32* __restrict__ nbr,
    const u16* __restrict__ hbT, const u16* __restrict__ vnbT,
    const int* __restrict__ batch, u16* __restrict__ ah, u16* __restrict__ alo) {
    const int s = blockIdx.x & 7;
    const int sub = blockIdx.x >> 3;
    const int f = s & 3;
    const int hs = s >> 2;
    const int lane = threadIdx.x & 63;
    const int w = threadIdx.x >> 6;
    const int g = lane >> 3, sl = lane & 7;
    const int pair = sl >> 2, fl = sl & 3;
    const int local = sub * 32 + w * 8 + g;
    if (local >= HNN) return;
    const int node = hs * HNN + local;

    const uint4* hT = (const uint4*)hbT + (size_t)f * NN * 4;   // 4 x uint4 per node
    const uint4* vT = (const uint4*)vnbT + (size_t)f * NB * 4;
    const u32* nbp = nbr + (size_t)node * DCAP;
    const int n = min(deg[node], DCAP);

    float acc[8];
    if (pair == 0) {
        uint4 hv = hT[(size_t)node * 4 + fl];
        uint4 vv = vT[(size_t)batch[node] * 4 + fl];
        acc[0] = bf2f(hv.x & 0xFFFFu) + bf2f(vv.x & 0xFFFFu);
        acc[1] = bf2f(hv.x >> 16) + bf2f(vv.x >> 16);
        acc[2] = bf2f(hv.y & 0xFFFFu) + bf2f(vv.y & 0xFFFFu);
        acc[3] = bf2f(hv.y >> 16) + bf2f(vv.y >> 16);
        acc[4] = bf2f(hv.z & 0xFFFFu) + bf2f(vv.z & 0xFFFFu);
        acc[5] = bf2f(hv.z >> 16) + bf2f(vv.z >> 16);
        acc[6] = bf2f(hv.w & 0xFFFFu) + bf2f(vv.w & 0xFFFFu);
        acc[7] = bf2f(hv.w >> 16) + bf2f(vv.w >> 16);
    } else {
#pragma unroll
        for (int i = 0; i < 8; ++i) acc[i] = 0.f;
    }

    int j = pair;
    for (; j + 2 < n; j += 4) {
        u32 e0 = nbp[j], e1 = nbp[j + 2];
        uint4 h0 = hT[(size_t)(e0 & 0xFFFFu) * 4 + fl];
        uint4 v0 = vT[(size_t)(e0 >> 16) * 4 + fl];
        uint4 h1 = hT[(size_t)(e1 & 0xFFFFu) * 4 + fl];
        uint4 v1 = vT[(size_t)(e1 >> 16) * 4 + fl];
        acc[0] += bf2f(h0.x & 0xFFFFu) + bf2f(v0.x & 0xFFFFu);
        acc[1] += bf2f(h0.x >> 16) + bf2f(v0.x >> 16);
        acc[2] += bf2f(h0.y & 0xFFFFu) + bf2f(v0.y & 0xFFFFu);
        acc[3] += bf2f(h0.y >> 16) + bf2f(v0.y >> 16);
        acc[4] += bf2f(h0.z & 0xFFFFu) + bf2f(v0.z & 0xFFFFu);
        acc[5] += bf2f(h0.z >> 16) + bf2f(v0.z >> 16);
        acc[6] += bf2f(h0.w & 0xFFFFu) + bf2f(v0.w & 0xFFFFu);
        acc[7] += bf2f(h0.w >> 16) + bf2f(v0.w >> 16);
        acc[0] += bf2f(h1.x & 0xFFFFu) + bf2f(v1.x & 0xFFFFu);
        acc[1] += bf2f(h1.x >> 16) + bf2f(v1.x >> 16);
        acc[2] += bf2f(h1.y & 0xFFFFu) + bf2f(v1.y & 0xFFFFu);
        acc[3] += bf2f(h1.y >> 16) + bf2f(v1.y >> 16);
        acc[4] += bf2f(h1.z & 0xFFFFu) + bf2f(v1.z & 0xFFFFu);
        acc[5] += bf2f(h1.z >> 16) + bf2f(v1.z >> 16);
        acc[6] += bf2f(h1.w & 0xFFFFu) + bf2f(v1.w & 0xFFFFu);
        acc[7] += bf2f(h1.w >> 16) + bf2f(v1.w >> 16);
    }
    if (j < n) {
        u32 e0 = nbp[j];
        uint4 h0 = hT[(size_t)(e0 & 0xFFFFu) * 4 + fl];
        uint4 v0 = vT[(size_t)(e0 >> 16) * 4 + fl];
        acc[0] += bf2f(h0.x & 0xFFFFu) + bf2f(v0.x & 0xFFFFu);
        acc[1] += bf2f(h0.x >> 16) + bf2f(v0.x >> 16);
        acc[2] += bf2f(h0.y & 0xFFFFu) + bf2f(v0.y & 0xFFFFu);
        acc[3] += bf2f(h0.y >> 16) + bf2f(v0.y >> 16);
        acc[4] += bf2f(h0.z & 0xFFFFu) + bf2f(v0.z & 0xFFFFu);
        acc[5] += bf2f(h0.z >> 16) + bf2f(v0.z >> 16);
        acc[6] += bf2f(h0.w & 0xFFFFu) + bf2f(v0.w & 0xFFFFu);
        acc[7] += bf2f(h0.w >> 16) + bf2f(v0.w >> 16);
    }

#pragma unroll
    for (int i = 0; i < 8; ++i) acc[i] += __shfl_xor(acc[i], 4);

    if (pair == 0) {
        u16 hi[8];
#pragma unroll
        for (int i = 0; i < 8; ++i) hi[i] = f2bf(acc[i]);
        uint4 ho = {(u32)hi[0] | ((u32)hi[1] << 16), (u32)hi[2] | ((u32)hi[3] << 16),
                    (u32)hi[4] | ((u32)hi[5] << 16), (u32)hi[6] | ((u32)hi[7] << 16)};
        uint4 lo = {pk2(acc[0] - bf2f(hi[0]), acc[1] - bf2f(hi[1])),
                    pk2(acc[2] - bf2f(hi[2]), acc[3] - bf2f(hi[3])),
                    pk2(acc[4] - bf2f(hi[4]), acc[5] - bf2f(hi[5])),
                    pk2(acc[6] - bf2f(hi[6]), acc[7] - bf2f(hi[7]))};
        const size_t oi = (size_t)node * 16 + f * 4 + fl;  // uint4 units, node-major
        ((uint4*)ah)[oi] = ho;
        ((uint4*)alo)[oi] = lo;
    }
}

// ---------------- MFMA GEMM: 256 rows/block, 512 threads ----------------
// AMODE: 0 = bf16 A (node-major), 1 = bf16 hi+lo split, 2 = f32 A split in-kernel
// EPI: 0 none, 1 leaky, 2 bn(leaky). OMODE: 0 = bf16 node-major, 1 = bf16 sliced.
template <int EPI, int AMODE, int OMODE>
__global__ __launch_bounds__(512) void k_gemm(
    const void* __restrict__ Ap, const void* __restrict__ Ap2,
    const u16* __restrict__ wt, const float* __restrict__ bias,
    const float* __restrict__ gg, const float* __restrict__ bb,
    u16* __restrict__ outp, int nrows) {
    __shared__ u16 sW[WT_M];
    const int t = threadIdx.x;
    {
        const float4* src = (const float4*)wt;
        float4* dst = (float4*)sW;
        for (int i = t; i < WT_M / 8; i += 512) dst[i] = src[i];
    }
    __syncthreads();
    const int lane = t & 63;
    const int w = t >> 6;  // 0..7
    const int rl = lane & 15;
    const int q = lane >> 4;
    const int rbase = blockIdx.x * 256 + w * 32;

    short8 af[2][4], al[2][4];
#pragma unroll
    for (int ri = 0; ri < 2; ++ri) {
        int row = min(rbase + ri * 16 + rl, nrows - 1);
#pragma unroll
        for (int kc = 0; kc < 4; ++kc) {
            if (AMODE == 2) {
                const float* ap = (const float*)Ap + (size_t)row * 128 + kc * 32 + q * 8;
                float4 f0 = *(const float4*)ap;
                float4 f1 = *(const float4*)(ap + 4);
                float fv[8] = {f0.x, f0.y, f0.z, f0.w, f1.x, f1.y, f1.z, f1.w};
                short8 hi, lo;
#pragma unroll
                for (int i = 0; i < 8; ++i) {
                    u16 hv = f2bf(fv[i]);
                    hi[i] = (short)hv;
                    lo[i] = (short)f2bf(fv[i] - bf2f(hv));
                }
                af[ri][kc] = hi;
                al[ri][kc] = lo;
            } else {
                af[ri][kc] = *(const short8*)((const u16*)Ap + (size_t)row * 128 + kc * 32 + q * 8);
                if (AMODE == 1)
                    al[ri][kc] = *(const short8*)((const u16*)Ap2 + (size_t)row * 128 + kc * 32 + q * 8);
            }
        }
    }

#pragma unroll
    for (int ct = 0; ct < 8; ++ct) {
        f32x4 acc0 = {0.f, 0.f, 0.f, 0.f};
        f32x4 acc1 = {0.f, 0.f, 0.f, 0.f};
#pragma unroll
        for (int kc = 0; kc < 4; ++kc) {
            short8 bf = *(const short8*)&sW[(ct * 16 + rl) * WT_S + kc * 32 + q * 8];
            if (AMODE != 0) {
                acc0 = __builtin_amdgcn_mfma_f32_16x16x32_bf16(al[0][kc], bf, acc0, 0, 0, 0);
                acc1 = __builtin_amdgcn_mfma_f32_16x16x32_bf16(al[1][kc], bf, acc1, 0, 0, 0);
            }
            acc0 = __builtin_amdgcn_mfma_f32_16x16x32_bf16(af[0][kc], bf, acc0, 0, 0, 0);
            acc1 = __builtin_amdgcn_mfma_f32_16x16x32_bf16(af[1][kc], bf, acc1, 0, 0, 0);
        }
        const int col = ct * 16 + rl;
        const float bs = bias[col];
        const float g = (EPI == 2) ? gg[col] : 0.f;
        const float be = (EPI == 2) ? bb[col] : 0.f;
#pragma unroll
        for (int half = 0; half < 2; ++half) {
            const f32x4& ac = half ? acc1 : acc0;
#pragma unroll
            for (int i = 0; i < 4; ++i) {
                int r = rbase + half * 16 + q * 4 + i;
                if (r < nrows) {
                    float v = ac[i] + bs;
                    if (EPI >= 1) v = v > 0.f ? v : 0.2f * v;
                    if (EPI == 2) v = g * v * BNS + be;
                    if (OMODE == 0)
                        outp[(size_t)r * 128 + col] = f2bf(v);
                    else
                        outp[((size_t)(col >> 5) * NN + r) * 32 + (col & 31)] = f2bf(v);
                }
            }
        }
    }
}

// ---------------- fused pool(sliced hbT) + vn MLP; writes vn + sliced bf16 mirror ----------------
__global__ __launch_bounds__(256) void k_vnup(
    const u16* __restrict__ hbT, const int* __restrict__ bstart,
    const float* __restrict__ counts, const float* __restrict__ W1,
    const float* __restrict__ b1, const float* __restrict__ W2,
    const float* __restrict__ b2, float* __restrict__ vn, u16* __restrict__ vnbT) {
    __shared__ float4 red[8][32];
    __shared__ float sP[128], sT[128], sH[2][128];
    const int b = blockIdx.x;
    const int t = threadIdx.x;
    const int s = bstart[b], e = bstart[b + 1];
    const int g = t >> 5, q = t & 31;
    const uint2* h2 = (const uint2*)hbT;
    const size_t fbase = (size_t)(q >> 3) * NN * 8;  // uint2 units
    const int fo = q & 7;
    float4 a = make_float4(0.f, 0.f, 0.f, 0.f);
    for (int r = s + g; r < e; r += 8) {
        uint2 v = h2[fbase + (size_t)r * 8 + fo];
        a.x += bf2f(v.x & 0xFFFFu); a.y += bf2f(v.x >> 16);
        a.z += bf2f(v.y & 0xFFFFu); a.w += bf2f(v.y >> 16);
    }
    red[g][q] = a;
    __syncthreads();
    if (g == 0) {
#pragma unroll
        for (int g2 = 1; g2 < 8; ++g2) {
            float4 v = red[g2][q];
            a.x += v.x; a.y += v.y; a.z += v.z; a.w += v.w;
        }
        float inv = 1.f / fmaxf(counts[b], 1.f);
        sP[q * 4 + 0] = a.x * inv;
        sP[q * 4 + 1] = a.y * inv;
        sP[q * 4 + 2] = a.z * inv;
        sP[q * 4 + 3] = a.w * inv;
    }
    __syncthreads();
    {
        const int c = t & 127, hf = t >> 7;
        float acc = 0.f;
        const float* Wp = W1 + (size_t)(hf * 64) * 128 + c;
#pragma unroll 8
        for (int k = 0; k < 64; ++k) acc += sP[hf * 64 + k] * Wp[(size_t)k * 128];
        sH[hf][c] = acc;
    }
    __syncthreads();
    if (t < 128) {
        float v = sH[0][t] + sH[1][t] + b1[t];
        sT[t] = v > 0.f ? v : 0.2f * v;
    }
    __syncthreads();
    {
        const int c = t & 127, hf = t >> 7;
        float acc = 0.f;
        const float* Wp = W2 + (size_t)(hf * 64) * 128 + c;
#pragma unroll 8
        for (int k = 0; k < 64; ++k) acc += sT[hf * 64 + k] * Wp[(size_t)k * 128];
        sH[hf][c] = acc;
    }
    __syncthreads();
    if (t < 128) {
        float nv = vn[(size_t)b * 128 + t] + sH[0][t] + sH[1][t] + b2[t];
        vn[(size_t)b * 128 + t] = nv;
        vnbT[((size_t)(t >> 5) * NB + b) * 32 + (t & 31)] = f2bf(nv);
    }
}

// ---------------- final: pool(sliced hbT) + BN + fc  (4 batches per block) ----------------
__global__ __launch_bounds__(256) void k_final(
    const u16* __restrict__ hbT, const int* __restrict__ bstart,
    const float* __restrict__ g, const float* __restrict__ bB,
    const float* __restrict__ fcW, const float* __restrict__ fcb,
    float* __restrict__ out) {
    __shared__ float sP[4][128];
    __shared__ float4 red[4][2][32];
    const int t = threadIdx.x;
    const int seg = t >> 6, gq = t & 63, rg = gq >> 5, q = gq & 31;
    const int b = blockIdx.x * 4 + seg;
    const int s = bstart[b], e = bstart[b + 1];
    const uint2* h2 = (const uint2*)hbT;
    const size_t fbase = (size_t)(q >> 3) * NN * 8;
    const int fo = q & 7;
    float4 a = make_float4(0.f, 0.f, 0.f, 0.f);
    for (int r = s + rg; r < e; r += 2) {
        uint2 v = h2[fbase + (size_t)r * 8 + fo];
        a.x += bf2f(v.x & 0xFFFFu); a.y += bf2f(v.x >> 16);
        a.z += bf2f(v.y & 0xFFFFu); a.w += bf2f(v.y >> 16);
    }
    red[seg][rg][q] = a;
    __syncthreads();
    if (rg == 0) {
        float4 v = red[seg][1][q];
        a.x += v.x; a.y += v.y; a.z += v.z; a.w += v.w;
        float av[4] = {a.x, a.y, a.z, a.w};
#pragma unroll
        for (int i = 0; i < 4; ++i) {
            int c = q * 4 + i;
            sP[seg][c] = g[c] * av[i] * BNS + bB[c];
        }
    }
    __syncthreads();
    const int o = t & 63;
    float acc = fcb[o];
    const float* wrow = fcW + o * 128;
    const float* prow = sP[seg];
    for (int k = 0; k < 128; ++k) acc += prow[k] * wrow[k];
    out[(size_t)b * 64 + o] = acc;
}

extern "C" void kernel_launch(void* const* d_in, const int* in_sizes, int n_in,
                              void* d_out, int out_size, void* d_ws, size_t ws_size,
                              hipStream_t stream) {
    const float* x       = (const float*)d_in[0];
    const int*   ei      = (const int*)d_in[1];
    const int*   batch   = (const int*)d_in[2];
    const float* node_W  = (const float*)d_in[3];
    const float* node_b  = (const float*)d_in[4];
    const float* conv_W1 = (const float*)d_in[5];
    const float* conv_b1 = (const float*)d_in[6];
    const float* conv_g  = (const float*)d_in[7];
    const float* conv_bt = (const float*)d_in[8];
    const float* conv_W2 = (const float*)d_in[9];
    const float* conv_b2 = (const float*)d_in[10];
    const float* vn_emb  = (const float*)d_in[11];
    const float* vn_W1   = (const float*)d_in[12];
    const float* vn_b1   = (const float*)d_in[13];
    const float* vn_W2   = (const float*)d_in[14];
    const float* vn_b2   = (const float*)d_in[15];
    const float* bn_g    = (const float*)d_in[16];
    const float* bn_b    = (const float*)d_in[17];
    const float* fc_W    = (const float*)d_in[18];
    const float* fc_b    = (const float*)d_in[19];
    float* out = (float*)d_out;

    char* ws = (char*)d_ws;
    u16* hbT   = (u16*)ws;                        // NN*128 bf16, feature-sliced
    u16* aggh  = hbT + (size_t)NN * 128;          // NN*128 bf16 node-major (agg hi / z)
    u16* agglo = aggh + (size_t)NN * 128;         // NN*128 bf16 node-major (agg lo)
    u16* wt    = agglo + (size_t)NN * 128;        // 7*WT_M bf16
    u32* nbr   = (u32*)(wt + 7 * WT_M);           // NN*DCAP u32 (padded CSR, src|batch<<16)
    float* vn  = (float*)(nbr + (size_t)NN * DCAP);  // NB*128 f32
    u16* vnbT  = (u16*)(vn + NB * 128);           // NB*128 bf16, feature-sliced
    float* counts = (float*)(vnbT + NB * 128);    // NB
    int* bstart = (int*)(counts + NB);            // NB+1
    int* deg    = bstart + NB + 1;                // NN  <- zeroed

    hipMemsetAsync(deg, 0, NN * sizeof(int), stream);
    k_prep<<<704, 256, 0, stream>>>(node_W, conv_W1, conv_W2, wt,
                                    vn_emb, vn, vnbT, batch, bstart, counts);
    k_pcsr<<<(NE + 255) / 256, 256, 0, stream>>>(ei, batch, deg, nbr);

    const int GG = (NN + 255) / 256;        // 196 gemm blocks
    const int GGA = 8 * ((HNN + 31) / 32);  // 8 slices x 782 = 6256 gather blocks

    // node encoder: hbT = sliced bf16(x @ node_W + node_b)
    k_gemm<0, 2, 1><<<GG, 512, 0, stream>>>(
        x, nullptr, wt, node_b, nullptr, nullptr, hbT, NN);

    for (int l = 0; l < 3; ++l) {
        // agg (vn folded in) -> hi/lo split, node-major
        k_gather<<<GGA, 256, 0, stream>>>(deg, nbr, hbT, vnbT, batch, aggh, agglo);
        // z = bn(leaky(agg @ W1 + b1)) -> bf16 node-major, in-place into aggh
        k_gemm<2, 1, 0><<<GG, 512, 0, stream>>>(
            aggh, agglo, wt + (size_t)(1 + l) * WT_M, conv_b1 + l * 128,
            conv_g + l * 128, conv_bt + l * 128, aggh, NN);
        // hbT = sliced bf16(leaky(z @ W2 + b2))
        k_gemm<1, 0, 1><<<GG, 512, 0, stream>>>(
            aggh, nullptr, wt + (size_t)(4 + l) * WT_M, conv_b2 + l * 128,
            nullptr, nullptr, hbT, NN);
        // vn += mlp(pool(hbT)/denom)   (dead for l=2 -> skip)
        if (l < 2)
            k_vnup<<<NB, 256, 0, stream>>>(hbT, bstart, counts, vn_W1 + l * 16384,
                                           vn_b1 + l * 128, vn_W2 + l * 16384,
                                           vn_b2 + l * 128, vn, vnbT);
    }

    k_final<<<NB / 4, 256, 0, stream>>>(hbT, bstart, bn_g, bn_b, fc_W, fc_b, out);
}

// Round 11
// 365.853 us; speedup vs baseline: 1.0080x; 1.0080x over previous
//
#include <hip/hip_runtime.h>
#include <hip/hip_bf16.h>

#define NN 50000
#define NE 800000
#define NB 512
#define HNN 25000          // nodes per half-slice
#define WT_S 136           // padded k-stride (bf16 elems) for transposed W
#define WT_M (128 * WT_S)  // elems per transposed weight matrix
#define DCAP 64            // padded CSR row capacity (deg ~ Poisson(16))

using u32 = unsigned int;
using u16 = unsigned short;
typedef __attribute__((ext_vector_type(8))) short short8;
typedef __attribute__((ext_vector_type(4))) float f32x4;

constexpr float BNS = 0.9999950000374998f;  // 1/sqrt(1+1e-5)

__device__ inline u16 f2bf(float f) {
    u32 b = __builtin_bit_cast(u32, f);
    return (u16)((b + 0x7FFFu + ((b >> 16) & 1u)) >> 16);
}
__device__ inline float bf2f(u32 u) {
    return __builtin_bit_cast(float, u << 16);
}
__device__ inline u32 pk2(float a, float b) {
    return (u32)f2bf(a) | ((u32)f2bf(b) << 16);
}

// sliced layouts: hbT[(fg*NN + node)*32 + (feat&31)], vnbT[(fg*NB + b)*32 + (feat&31)]

// ---------------- fused prep: wprep (blocks 0..447) + setup (blocks 448..703) ----------------
__global__ void k_prep(const float* __restrict__ nW, const float* __restrict__ cW1,
                       const float* __restrict__ cW2, u16* __restrict__ wt,
                       const float* __restrict__ vn_emb, float* __restrict__ vn,
                       u16* __restrict__ vnbT, const int* __restrict__ batch,
                       int* __restrict__ bstart, float* __restrict__ counts) {
    if (blockIdx.x < 448) {
        int idx = blockIdx.x * 256 + threadIdx.x;  // < 7*16384
        int m = idx >> 14, e = idx & 16383;
        int k = e >> 7, c = e & 127;
        const float* src = m == 0 ? nW : (m <= 3 ? cW1 + (m - 1) * 16384 : cW2 + (m - 4) * 16384);
        wt[m * WT_M + c * WT_S + k] = f2bf(src[e]);
        return;
    }
    int idx = (blockIdx.x - 448) * 256 + threadIdx.x;
    if (idx < NB * 128) {
        int b = idx >> 7, c = idx & 127;
        float v = vn_emb[c];
        vn[idx] = v;
        vnbT[((size_t)(c >> 5) * NB + b) * 32 + (c & 31)] = f2bf(v);
    }
    if (idx <= NB) {
        int b = idx;
        int lo = 0, hi = NN;
        while (lo < hi) { int m = (lo + hi) >> 1; if (batch[m] < b) lo = m + 1; else hi = m; }
        bstart[b] = lo;
        if (b < NB) {
            int b1 = b + 1, lo1 = 0, hi1 = NN;
            while (lo1 < hi1) { int m = (lo1 + hi1) >> 1; if (batch[m] < b1) lo1 = m + 1; else hi1 = m; }
            counts[b] = (float)(lo1 - lo);
        }
    }
}

// ---------------- padded CSR: one-pass scatter; entry = src | batch[src]<<16 ----------------
__global__ void k_pcsr(const int* __restrict__ ei, const int* __restrict__ batch,
                       int* __restrict__ deg, u32* __restrict__ nbr) {
    int e = blockIdx.x * 256 + threadIdx.x;
    if (e >= NE) return;
    int src = ei[e];
    int dst = ei[NE + e];
    int pos = atomicAdd(&deg[dst], 1);
    if (pos < DCAP) nbr[(size_t)dst * DCAP + pos] = (u32)src | ((u32)batch[src] << 16);
}

// ---------------- gather (XCD-pinned, feature-sliced inputs) ----------------
// slice s = bid&7: fgroup f = s&3 (features f*32..f*32+31), half hs = s>>2.
// 8 lanes/node: 4 flanes x 2 neighbor-pairs; shfl_xor(4) combine.
__global__ __launch_bounds__(256) void k_gather(
    const int* __restrict__ deg, const u32* __restrict__ nbr,
    const u16* __restrict__ hbT, const u16* __restrict__ vnbT,
    const int* __restrict__ batch, u16* __restrict__ ah, u16* __restrict__ alo) {
    const int s = blockIdx.x & 7;
    const int sub = blockIdx.x >> 3;
    const int f = s & 3;
    const int hs = s >> 2;
    const int lane = threadIdx.x & 63;
    const int w = threadIdx.x >> 6;
    const int g = lane >> 3, sl = lane & 7;
    const int pair = sl >> 2, fl = sl & 3;
    const int local = sub * 32 + w * 8 + g;
    if (local >= HNN) return;
    const int node = hs * HNN + local;

    const uint4* hT = (const uint4*)hbT + (size_t)f * NN * 4;   // 4 x uint4 per node
    const uint4* vT = (const uint4*)vnbT + (size_t)f * NB * 4;
    const u32* nbp = nbr + (size_t)node * DCAP;
    const int n = min(deg[node], DCAP);

    float acc[8];
    if (pair == 0) {
        uint4 hv = hT[(size_t)node * 4 + fl];
        uint4 vv = vT[(size_t)batch[node] * 4 + fl];
        acc[0] = bf2f(hv.x & 0xFFFFu) + bf2f(vv.x & 0xFFFFu);
        acc[1] = bf2f(hv.x >> 16) + bf2f(vv.x >> 16);
        acc[2] = bf2f(hv.y & 0xFFFFu) + bf2f(vv.y & 0xFFFFu);
        acc[3] = bf2f(hv.y >> 16) + bf2f(vv.y >> 16);
        acc[4] = bf2f(hv.z & 0xFFFFu) + bf2f(vv.z & 0xFFFFu);
        acc[5] = bf2f(hv.z >> 16) + bf2f(vv.z >> 16);
        acc[6] = bf2f(hv.w & 0xFFFFu) + bf2f(vv.w & 0xFFFFu);
        acc[7] = bf2f(hv.w >> 16) + bf2f(vv.w >> 16);
    } else {
#pragma unroll
        for (int i = 0; i < 8; ++i) acc[i] = 0.f;
    }

    int j = pair;
    for (; j + 2 < n; j += 4) {
        u32 e0 = nbp[j], e1 = nbp[j + 2];
        uint4 h0 = hT[(size_t)(e0 & 0xFFFFu) * 4 + fl];
        uint4 v0 = vT[(size_t)(e0 >> 16) * 4 + fl];
        uint4 h1 = hT[(size_t)(e1 & 0xFFFFu) * 4 + fl];
        uint4 v1 = vT[(size_t)(e1 >> 16) * 4 + fl];
        acc[0] += bf2f(h0.x & 0xFFFFu) + bf2f(v0.x & 0xFFFFu);
        acc[1] += bf2f(h0.x >> 16) + bf2f(v0.x >> 16);
        acc[2] += bf2f(h0.y & 0xFFFFu) + bf2f(v0.y & 0xFFFFu);
        acc[3] += bf2f(h0.y >> 16) + bf2f(v0.y >> 16);
        acc[4] += bf2f(h0.z & 0xFFFFu) + bf2f(v0.z & 0xFFFFu);
        acc[5] += bf2f(h0.z >> 16) + bf2f(v0.z >> 16);
        acc[6] += bf2f(h0.w & 0xFFFFu) + bf2f(v0.w & 0xFFFFu);
        acc[7] += bf2f(h0.w >> 16) + bf2f(v0.w >> 16);
        acc[0] += bf2f(h1.x & 0xFFFFu) + bf2f(v1.x & 0xFFFFu);
        acc[1] += bf2f(h1.x >> 16) + bf2f(v1.x >> 16);
        acc[2] += bf2f(h1.y & 0xFFFFu) + bf2f(v1.y & 0xFFFFu);
        acc[3] += bf2f(h1.y >> 16) + bf2f(v1.y >> 16);
        acc[4] += bf2f(h1.z & 0xFFFFu) + bf2f(v1.z & 0xFFFFu);
        acc[5] += bf2f(h1.z >> 16) + bf2f(v1.z >> 16);
        acc[6] += bf2f(h1.w & 0xFFFFu) + bf2f(v1.w & 0xFFFFu);
        acc[7] += bf2f(h1.w >> 16) + bf2f(v1.w >> 16);
    }
    if (j < n) {
        u32 e0 = nbp[j];
        uint4 h0 = hT[(size_t)(e0 & 0xFFFFu) * 4 + fl];
        uint4 v0 = vT[(size_t)(e0 >> 16) * 4 + fl];
        acc[0] += bf2f(h0.x & 0xFFFFu) + bf2f(v0.x & 0xFFFFu);
        acc[1] += bf2f(h0.x >> 16) + bf2f(v0.x >> 16);
        acc[2] += bf2f(h0.y & 0xFFFFu) + bf2f(v0.y & 0xFFFFu);
        acc[3] += bf2f(h0.y >> 16) + bf2f(v0.y >> 16);
        acc[4] += bf2f(h0.z & 0xFFFFu) + bf2f(v0.z & 0xFFFFu);
        acc[5] += bf2f(h0.z >> 16) + bf2f(v0.z >> 16);
        acc[6] += bf2f(h0.w & 0xFFFFu) + bf2f(v0.w & 0xFFFFu);
        acc[7] += bf2f(h0.w >> 16) + bf2f(v0.w >> 16);
    }

#pragma unroll
    for (int i = 0; i < 8; ++i) acc[i] += __shfl_xor(acc[i], 4);

    if (pair == 0) {
        u16 hi[8];
#pragma unroll
        for (int i = 0; i < 8; ++i) hi[i] = f2bf(acc[i]);
        uint4 ho = {(u32)hi[0] | ((u32)hi[1] << 16), (u32)hi[2] | ((u32)hi[3] << 16),
                    (u32)hi[4] | ((u32)hi[5] << 16), (u32)hi[6] | ((u32)hi[7] << 16)};
        uint4 lo = {pk2(acc[0] - bf2f(hi[0]), acc[1] - bf2f(hi[1])),
                    pk2(acc[2] - bf2f(hi[2]), acc[3] - bf2f(hi[3])),
                    pk2(acc[4] - bf2f(hi[4]), acc[5] - bf2f(hi[5])),
                    pk2(acc[6] - bf2f(hi[6]), acc[7] - bf2f(hi[7]))};
        const size_t oi = (size_t)node * 16 + f * 4 + fl;  // uint4 units, node-major
        ((uint4*)ah)[oi] = ho;
        ((uint4*)alo)[oi] = lo;
    }
}

// ---------------- MFMA GEMM: 256 rows/block, 512 threads ----------------
// AMODE: 0 = bf16 A (node-major), 1 = bf16 hi+lo split, 2 = f32 A split in-kernel
// EPI: 0 none, 1 leaky, 2 bn(leaky). OMODE: 0 = bf16 node-major, 1 = bf16 sliced.
template <int EPI, int AMODE, int OMODE>
__global__ __launch_bounds__(512) void k_gemm(
    const void* __restrict__ Ap, const void* __restrict__ Ap2,
    const u16* __restrict__ wt, const float* __restrict__ bias,
    const float* __restrict__ gg, const float* __restrict__ bb,
    u16* __restrict__ outp, int nrows) {
    __shared__ u16 sW[WT_M];
    const int t = threadIdx.x;
    {
        const float4* src = (const float4*)wt;
        float4* dst = (float4*)sW;
        for (int i = t; i < WT_M / 8; i += 512) dst[i] = src[i];
    }
    __syncthreads();
    const int lane = t & 63;
    const int w = t >> 6;  // 0..7
    const int rl = lane & 15;
    const int q = lane >> 4;
    const int rbase = blockIdx.x * 256 + w * 32;

    short8 af[2][4], al[2][4];
#pragma unroll
    for (int ri = 0; ri < 2; ++ri) {
        int row = min(rbase + ri * 16 + rl, nrows - 1);
#pragma unroll
        for (int kc = 0; kc < 4; ++kc) {
            if (AMODE == 2) {
                const float* ap = (const float*)Ap + (size_t)row * 128 + kc * 32 + q * 8;
                float4 f0 = *(const float4*)ap;
                float4 f1 = *(const float4*)(ap + 4);
                float fv[8] = {f0.x, f0.y, f0.z, f0.w, f1.x, f1.y, f1.z, f1.w};
                short8 hi, lo;
#pragma unroll
                for (int i = 0; i < 8; ++i) {
                    u16 hv = f2bf(fv[i]);
                    hi[i] = (short)hv;
                    lo[i] = (short)f2bf(fv[i] - bf2f(hv));
                }
                af[ri][kc] = hi;
                al[ri][kc] = lo;
            } else {
                af[ri][kc] = *(const short8*)((const u16*)Ap + (size_t)row * 128 + kc * 32 + q * 8);
                if (AMODE == 1)
                    al[ri][kc] = *(const short8*)((const u16*)Ap2 + (size_t)row * 128 + kc * 32 + q * 8);
            }
        }
    }

#pragma unroll
    for (int ct = 0; ct < 8; ++ct) {
        f32x4 acc0 = {0.f, 0.f, 0.f, 0.f};
        f32x4 acc1 = {0.f, 0.f, 0.f, 0.f};
#pragma unroll
        for (int kc = 0; kc < 4; ++kc) {
            short8 bf = *(const short8*)&sW[(ct * 16 + rl) * WT_S + kc * 32 + q * 8];
            if (AMODE != 0) {
                acc0 = __builtin_amdgcn_mfma_f32_16x16x32_bf16(al[0][kc], bf, acc0, 0, 0, 0);
                acc1 = __builtin_amdgcn_mfma_f32_16x16x32_bf16(al[1][kc], bf, acc1, 0, 0, 0);
            }
            acc0 = __builtin_amdgcn_mfma_f32_16x16x32_bf16(af[0][kc], bf, acc0, 0, 0, 0);
            acc1 = __builtin_amdgcn_mfma_f32_16x16x32_bf16(af[1][kc], bf, acc1, 0, 0, 0);
        }
        const int col = ct * 16 + rl;
        const float bs = bias[col];
        const float g = (EPI == 2) ? gg[col] : 0.f;
        const float be = (EPI == 2) ? bb[col] : 0.f;
#pragma unroll
        for (int half = 0; half < 2; ++half) {
            const f32x4& ac = half ? acc1 : acc0;
#pragma unroll
            for (int i = 0; i < 4; ++i) {
                int r = rbase + half * 16 + q * 4 + i;
                if (r < nrows) {
                    float v = ac[i] + bs;
                    if (EPI >= 1) v = v > 0.f ? v : 0.2f * v;
                    if (EPI == 2) v = g * v * BNS + be;
                    if (OMODE == 0)
                        outp[(size_t)r * 128 + col] = f2bf(v);
                    else
                        outp[((size_t)(col >> 5) * NN + r) * 32 + (col & 31)] = f2bf(v);
                }
            }
        }
    }
}

// ---------------- fused pool(sliced hbT) + vn MLP; writes vn + sliced bf16 mirror ----------------
__global__ __launch_bounds__(256) void k_vnup(
    const u16* __restrict__ hbT, const int* __restrict__ bstart,
    const float* __restrict__ counts, const float* __restrict__ W1,
    const float* __restrict__ b1, const float* __restrict__ W2,
    const float* __restrict__ b2, float* __restrict__ vn, u16* __restrict__ vnbT) {
    __shared__ float4 red[8][32];
    __shared__ float sP[128], sT[128], sH[2][128];
    const int b = blockIdx.x;
    const int t = threadIdx.x;
    const int s = bstart[b], e = bstart[b + 1];
    const int g = t >> 5, q = t & 31;
    const uint2* h2 = (const uint2*)hbT;
    const size_t fbase = (size_t)(q >> 3) * NN * 8;  // uint2 units
    const int fo = q & 7;
    float4 a = make_float4(0.f, 0.f, 0.f, 0.f);
    for (int r = s + g; r < e; r += 8) {
        uint2 v = h2[fbase + (size_t)r * 8 + fo];
        a.x += bf2f(v.x & 0xFFFFu); a.y += bf2f(v.x >> 16);
        a.z += bf2f(v.y & 0xFFFFu); a.w += bf2f(v.y >> 16);
    }
    red[g][q] = a;
    __syncthreads();
    if (g == 0) {
#pragma unroll
        for (int g2 = 1; g2 < 8; ++g2) {
            float4 v = red[g2][q];
            a.x += v.x; a.y += v.y; a.z += v.z; a.w += v.w;
        }
        float inv = 1.f / fmaxf(counts[b], 1.f);
        sP[q * 4 + 0] = a.x * inv;
        sP[q * 4 + 1] = a.y * inv;
        sP[q * 4 + 2] = a.z * inv;
        sP[q * 4 + 3] = a.w * inv;
    }
    __syncthreads();
    {
        const int c = t & 127, hf = t >> 7;
        float acc = 0.f;
        const float* Wp = W1 + (size_t)(hf * 64) * 128 + c;
#pragma unroll 8
        for (int k = 0; k < 64; ++k) acc += sP[hf * 64 + k] * Wp[(size_t)k * 128];
        sH[hf][c] = acc;
    }
    __syncthreads();
    if (t < 128) {
        float v = sH[0][t] + sH[1][t] + b1[t];
        sT[t] = v > 0.f ? v : 0.2f * v;
    }
    __syncthreads();
    {
        const int c = t & 127, hf = t >> 7;
        float acc = 0.f;
        const float* Wp = W2 + (size_t)(hf * 64) * 128 + c;
#pragma unroll 8
        for (int k = 0; k < 64; ++k) acc += sT[hf * 64 + k] * Wp[(size_t)k * 128];
        sH[hf][c] = acc;
    }
    __syncthreads();
    if (t < 128) {
        float nv = vn[(size_t)b * 128 + t] + sH[0][t] + sH[1][t] + b2[t];
        vn[(size_t)b * 128 + t] = nv;
        vnbT[((size_t)(t >> 5) * NB + b) * 32 + (t & 31)] = f2bf(nv);
    }
}

// ---------------- final: pool(sliced hbT) + BN + fc  (4 batches per block) ----------------
__global__ __launch_bounds__(256) void k_final(
    const u16* __restrict__ hbT, const int* __restrict__ bstart,
    const float* __restrict__ g, const float* __restrict__ bB,
    const float* __restrict__ fcW, const float* __restrict__ fcb,
    float* __restrict__ out) {
    __shared__ float sP[4][128];
    __shared__ float4 red[4][2][32];
    const int t = threadIdx.x;
    const int seg = t >> 6, gq = t & 63, rg = gq >> 5, q = gq & 31;
    const int b = blockIdx.x * 4 + seg;
    const int s = bstart[b], e = bstart[b + 1];
    const uint2* h2 = (const uint2*)hbT;
    const size_t fbase = (size_t)(q >> 3) * NN * 8;
    const int fo = q & 7;
    float4 a = make_float4(0.f, 0.f, 0.f, 0.f);
    for (int r = s + rg; r < e; r += 2) {
        uint2 v = h2[fbase + (size_t)r * 8 + fo];
        a.x += bf2f(v.x & 0xFFFFu); a.y += bf2f(v.x >> 16);
        a.z += bf2f(v.y & 0xFFFFu); a.w += bf2f(v.y >> 16);
    }
    red[seg][rg][q] = a;
    __syncthreads();
    if (rg == 0) {
        float4 v = red[seg][1][q];
        a.x += v.x; a.y += v.y; a.z += v.z; a.w += v.w;
        float av[4] = {a.x, a.y, a.z, a.w};
#pragma unroll
        for (int i = 0; i < 4; ++i) {
            int c = q * 4 + i;
            sP[seg][c] = g[c] * av[i] * BNS + bB[c];
        }
    }
    __syncthreads();
    const int o = t & 63;
    float acc = fcb[o];
    const float* wrow = fcW + o * 128;
    const float* prow = sP[seg];
    for (int k = 0; k < 128; ++k) acc += prow[k] * wrow[k];
    out[(size_t)b * 64 + o] = acc;
}

extern "C" void kernel_launch(void* const* d_in, const int* in_sizes, int n_in,
                              void* d_out, int out_size, void* d_ws, size_t ws_size,
                              hipStream_t stream) {
    const float* x       = (const float*)d_in[0];
    const int*   ei      = (const int*)d_in[1];
    const int*   batch   = (const int*)d_in[2];
    const float* node_W  = (const float*)d_in[3];
    const float* node_b  = (const float*)d_in[4];
    const float* conv_W1 = (const float*)d_in[5];
    const float* conv_b1 = (const float*)d_in[6];
    const float* conv_g  = (const float*)d_in[7];
    const float* conv_bt = (const float*)d_in[8];
    const float* conv_W2 = (const float*)d_in[9];
    const float* conv_b2 = (const float*)d_in[10];
    const float* vn_emb  = (const float*)d_in[11];
    const float* vn_W1   = (const float*)d_in[12];
    const float* vn_b1   = (const float*)d_in[13];
    const float* vn_W2   = (const float*)d_in[14];
    const float* vn_b2   = (const float*)d_in[15];
    const float* bn_g    = (const float*)d_in[16];
    const float* bn_b    = (const float*)d_in[17];
    const float* fc_W    = (const float*)d_in[18];
    const float* fc_b    = (const float*)d_in[19];
    float* out = (float*)d_out;

    char* ws = (char*)d_ws;
    u16* hbT   = (u16*)ws;                        // NN*128 bf16, feature-sliced
    u16* aggh  = hbT + (size_t)NN * 128;          // NN*128 bf16 node-major (agg hi / z)
    u16* agglo = aggh + (size_t)NN * 128;         // NN*128 bf16 node-major (agg lo)
    u16* wt    = agglo + (size_t)NN * 128;        // 7*WT_M bf16
    u32* nbr   = (u32*)(wt + 7 * WT_M);           // NN*DCAP u32 (padded CSR, src|batch<<16)
    float* vn  = (float*)(nbr + (size_t)NN * DCAP);  // NB*128 f32
    u16* vnbT  = (u16*)(vn + NB * 128);           // NB*128 bf16, feature-sliced
    float* counts = (float*)(vnbT + NB * 128);    // NB
    int* bstart = (int*)(counts + NB);            // NB+1
    int* deg    = bstart + NB + 1;                // NN  <- zeroed

    hipMemsetAsync(deg, 0, NN * sizeof(int), stream);
    k_prep<<<704, 256, 0, stream>>>(node_W, conv_W1, conv_W2, wt,
                                    vn_emb, vn, vnbT, batch, bstart, counts);
    k_pcsr<<<(NE + 255) / 256, 256, 0, stream>>>(ei, batch, deg, nbr);

    const int GG = (NN + 255) / 256;        // 196 gemm blocks
    const int GGA = 8 * ((HNN + 31) / 32);  // 8 slices x 782 = 6256 gather blocks

    // node encoder: hbT = sliced bf16(x @ node_W + node_b)
    k_gemm<0, 2, 1><<<GG, 512, 0, stream>>>(
        x, nullptr, wt, node_b, nullptr, nullptr, hbT, NN);

    for (int l = 0; l < 3; ++l) {
        // agg (vn folded in) -> hi/lo split, node-major
        k_gather<<<GGA, 256, 0, stream>>>(deg, nbr, hbT, vnbT, batch, aggh, agglo);
        // z = bn(leaky(agg @ W1 + b1)) -> bf16 node-major, in-place into aggh
        k_gemm<2, 1, 0><<<GG, 512, 0, stream>>>(
            aggh, agglo, wt + (size_t)(1 + l) * WT_M, conv_b1 + l * 128,
            conv_g + l * 128, conv_bt + l * 128, aggh, NN);
        // hbT = sliced bf16(leaky(z @ W2 + b2))
        k_gemm<1, 0, 1><<<GG, 512, 0, stream>>>(
            aggh, nullptr, wt + (size_t)(4 + l) * WT_M, conv_b2 + l * 128,
            nullptr, nullptr, hbT, NN);
        // vn += mlp(pool(hbT)/denom)   (dead for l=2 -> skip)
        if (l < 2)
            k_vnup<<<NB, 256, 0, stream>>>(hbT, bstart, counts, vn_W1 + l * 16384,
                                           vn_b1 + l * 128, vn_W2 + l * 16384,
                                           vn_b2 + l * 128, vn, vnbT);
    }

    k_final<<<NB / 4, 256, 0, stream>>>(hbT, bstart, bn_g, bn_b, fc_W, fc_b, out);
}

// Round 12
// 365.497 us; speedup vs baseline: 1.0089x; 1.0010x over previous
//
#include <hip/hip_runtime.h>
#include <hip/hip_bf16.h>

#define NN 50000
#define NE 800000
#define NB 512
#define HNN 25000          // nodes per half-slice
#define WT_S 136           // padded k-stride (bf16 elems) for transposed W
#define WT_M (128 * WT_S)  // elems per transposed weight matrix
#define DCAP 64            // padded CSR row capacity (deg ~ Poisson(16))

using u32 = unsigned int;
using u16 = unsigned short;
typedef __attribute__((ext_vector_type(8))) short short8;
typedef __attribute__((ext_vector_type(4))) float f32x4;

constexpr float BNS = 0.9999950000374998f;  // 1/sqrt(1+1e-5)

__device__ inline u16 f2bf(float f) {
    u32 b = __builtin_bit_cast(u32, f);
    return (u16)((b + 0x7FFFu + ((b >> 16) & 1u)) >> 16);
}
__device__ inline float bf2f(u32 u) {
    return __builtin_bit_cast(float, u << 16);
}
__device__ inline u32 pk2(float a, float b) {
    return (u32)f2bf(a) | ((u32)f2bf(b) << 16);
}

// sliced layouts: hbT[(fg*NN + node)*32 + (feat&31)], vnbT[(fg*NB + b)*32 + (feat&31)]

// ---------------- fused prep: wprep (blocks 0..447) + setup (blocks 448..703) ----------------
__global__ void k_prep(const float* __restrict__ nW, const float* __restrict__ cW1,
                       const float* __restrict__ cW2, u16* __restrict__ wt,
                       const float* __restrict__ vn_emb, float* __restrict__ vn,
                       u16* __restrict__ vnbT, const int* __restrict__ batch,
                       int* __restrict__ bstart, float* __restrict__ counts) {
    if (blockIdx.x < 448) {
        int idx = blockIdx.x * 256 + threadIdx.x;  // < 7*16384
        int m = idx >> 14, e = idx & 16383;
        int k = e >> 7, c = e & 127;
        const float* src = m == 0 ? nW : (m <= 3 ? cW1 + (m - 1) * 16384 : cW2 + (m - 4) * 16384);
        wt[m * WT_M + c * WT_S + k] = f2bf(src[e]);
        return;
    }
    int idx = (blockIdx.x - 448) * 256 + threadIdx.x;
    if (idx < NB * 128) {
        int b = idx >> 7, c = idx & 127;
        float v = vn_emb[c];
        vn[idx] = v;
        vnbT[((size_t)(c >> 5) * NB + b) * 32 + (c & 31)] = f2bf(v);
    }
    if (idx <= NB) {
        int b = idx;
        int lo = 0, hi = NN;
        while (lo < hi) { int m = (lo + hi) >> 1; if (batch[m] < b) lo = m + 1; else hi = m; }
        bstart[b] = lo;
        if (b < NB) {
            int b1 = b + 1, lo1 = 0, hi1 = NN;
            while (lo1 < hi1) { int m = (lo1 + hi1) >> 1; if (batch[m] < b1) lo1 = m + 1; else hi1 = m; }
            counts[b] = (float)(lo1 - lo);
        }
    }
}

// ---------------- padded CSR: one-pass scatter; entry = src | batch[src]<<16 ----------------
__global__ void k_pcsr(const int* __restrict__ ei, const int* __restrict__ batch,
                       int* __restrict__ deg, u32* __restrict__ nbr) {
    int e = blockIdx.x * 256 + threadIdx.x;
    if (e >= NE) return;
    int src = ei[e];
    int dst = ei[NE + e];
    int pos = atomicAdd(&deg[dst], 1);
    if (pos < DCAP) nbr[(size_t)dst * DCAP + pos] = (u32)src | ((u32)batch[src] << 16);
}

// ---------------- gather (XCD-pinned, feature-sliced inputs) ----------------
// slice s = bid&7: fgroup f = s&3 (features f*32..f*32+31), half hs = s>>2.
// 8 lanes/node: 4 flanes x 2 neighbor-pairs; shfl_xor(4) combine.
__global__ __launch_bounds__(256) void k_gather(
    const int* __restrict__ deg, const u32* __restrict__ nbr,
    const u16* __restrict__ hbT, const u16* __restrict__ vnbT,
    const int* __restrict__ batch, u16* __restrict__ ah, u16* __restrict__ alo) {
    const int s = blockIdx.x & 7;
    const int sub = blockIdx.x >> 3;
    const int f = s & 3;
    const int hs = s >> 2;
    const int lane = threadIdx.x & 63;
    const int w = threadIdx.x >> 6;
    const int g = lane >> 3, sl = lane & 7;
    const int pair = sl >> 2, fl = sl & 3;
    const int local = sub * 32 + w * 8 + g;
    if (local >= HNN) return;
    const int node = hs * HNN + local;

    const uint4* hT = (const uint4*)hbT + (size_t)f * NN * 4;   // 4 x uint4 per node
    const uint4* vT = (const uint4*)vnbT + (size_t)f * NB * 4;
    const u32* nbp = nbr + (size_t)node * DCAP;
    const int n = min(deg[node], DCAP);

    float acc[8];
    if (pair == 0) {
        uint4 hv = hT[(size_t)node * 4 + fl];
        uint4 vv = vT[(size_t)batch[node] * 4 + fl];
        acc[0] = bf2f(hv.x & 0xFFFFu) + bf2f(vv.x & 0xFFFFu);
        acc[1] = bf2f(hv.x >> 16) + bf2f(vv.x >> 16);
        acc[2] = bf2f(hv.y & 0xFFFFu) + bf2f(vv.y & 0xFFFFu);
        acc[3] = bf2f(hv.y >> 16) + bf2f(vv.y >> 16);
        acc[4] = bf2f(hv.z & 0xFFFFu) + bf2f(vv.z & 0xFFFFu);
        acc[5] = bf2f(hv.z >> 16) + bf2f(vv.z >> 16);
        acc[6] = bf2f(hv.w & 0xFFFFu) + bf2f(vv.w & 0xFFFFu);
        acc[7] = bf2f(hv.w >> 16) + bf2f(vv.w >> 16);
    } else {
#pragma unroll
        for (int i = 0; i < 8; ++i) acc[i] = 0.f;
    }

    int j = pair;
    for (; j + 2 < n; j += 4) {
        u32 e0 = nbp[j], e1 = nbp[j + 2];
        uint4 h0 = hT[(size_t)(e0 & 0xFFFFu) * 4 + fl];
        uint4 v0 = vT[(size_t)(e0 >> 16) * 4 + fl];
        uint4 h1 = hT[(size_t)(e1 & 0xFFFFu) * 4 + fl];
        uint4 v1 = vT[(size_t)(e1 >> 16) * 4 + fl];
        acc[0] += bf2f(h0.x & 0xFFFFu) + bf2f(v0.x & 0xFFFFu);
        acc[1] += bf2f(h0.x >> 16) + bf2f(v0.x >> 16);
        acc[2] += bf2f(h0.y & 0xFFFFu) + bf2f(v0.y & 0xFFFFu);
        acc[3] += bf2f(h0.y >> 16) + bf2f(v0.y >> 16);
        acc[4] += bf2f(h0.z & 0xFFFFu) + bf2f(v0.z & 0xFFFFu);
        acc[5] += bf2f(h0.z >> 16) + bf2f(v0.z >> 16);
        acc[6] += bf2f(h0.w & 0xFFFFu) + bf2f(v0.w & 0xFFFFu);
        acc[7] += bf2f(h0.w >> 16) + bf2f(v0.w >> 16);
        acc[0] += bf2f(h1.x & 0xFFFFu) + bf2f(v1.x & 0xFFFFu);
        acc[1] += bf2f(h1.x >> 16) + bf2f(v1.x >> 16);
        acc[2] += bf2f(h1.y & 0xFFFFu) + bf2f(v1.y & 0xFFFFu);
        acc[3] += bf2f(h1.y >> 16) + bf2f(v1.y >> 16);
        acc[4] += bf2f(h1.z & 0xFFFFu) + bf2f(v1.z & 0xFFFFu);
        acc[5] += bf2f(h1.z >> 16) + bf2f(v1.z >> 16);
        acc[6] += bf2f(h1.w & 0xFFFFu) + bf2f(v1.w & 0xFFFFu);
        acc[7] += bf2f(h1.w >> 16) + bf2f(v1.w >> 16);
    }
    if (j < n) {
        u32 e0 = nbp[j];
        uint4 h0 = hT[(size_t)(e0 & 0xFFFFu) * 4 + fl];
        uint4 v0 = vT[(size_t)(e0 >> 16) * 4 + fl];
        acc[0] += bf2f(h0.x & 0xFFFFu) + bf2f(v0.x & 0xFFFFu);
        acc[1] += bf2f(h0.x >> 16) + bf2f(v0.x >> 16);
        acc[2] += bf2f(h0.y & 0xFFFFu) + bf2f(v0.y & 0xFFFFu);
        acc[3] += bf2f(h0.y >> 16) + bf2f(v0.y >> 16);
        acc[4] += bf2f(h0.z & 0xFFFFu) + bf2f(v0.z & 0xFFFFu);
        acc[5] += bf2f(h0.z >> 16) + bf2f(v0.z >> 16);
        acc[6] += bf2f(h0.w & 0xFFFFu) + bf2f(v0.w & 0xFFFFu);
        acc[7] += bf2f(h0.w >> 16) + bf2f(v0.w >> 16);
    }

#pragma unroll
    for (int i = 0; i < 8; ++i) acc[i] += __shfl_xor(acc[i], 4);

    if (pair == 0) {
        u16 hi[8];
#pragma unroll
        for (int i = 0; i < 8; ++i) hi[i] = f2bf(acc[i]);
        uint4 ho = {(u32)hi[0] | ((u32)hi[1] << 16), (u32)hi[2] | ((u32)hi[3] << 16),
                    (u32)hi[4] | ((u32)hi[5] << 16), (u32)hi[6] | ((u32)hi[7] << 16)};
        uint4 lo = {pk2(acc[0] - bf2f(hi[0]), acc[1] - bf2f(hi[1])),
                    pk2(acc[2] - bf2f(hi[2]), acc[3] - bf2f(hi[3])),
                    pk2(acc[4] - bf2f(hi[4]), acc[5] - bf2f(hi[5])),
                    pk2(acc[6] - bf2f(hi[6]), acc[7] - bf2f(hi[7]))};
        const size_t oi = (size_t)node * 16 + f * 4 + fl;  // uint4 units, node-major
        ((uint4*)ah)[oi] = ho;
        ((uint4*)alo)[oi] = lo;
    }
}

// ---------------- MFMA GEMM: 256 rows/block, 512 threads ----------------
// AMODE: 0 = bf16 A (node-major), 1 = bf16 hi+lo split, 2 = f32 A split in-kernel
// EPI: 0 none, 1 leaky, 2 bn(leaky). OMODE: 0 = bf16 node-major, 1 = bf16 sliced.
template <int EPI, int AMODE, int OMODE>
__global__ __launch_bounds__(512) void k_gemm(
    const void* __restrict__ Ap, const void* __restrict__ Ap2,
    const u16* __restrict__ wt, const float* __restrict__ bias,
    const float* __restrict__ gg, const float* __restrict__ bb,
    u16* __restrict__ outp, int nrows) {
    __shared__ u16 sW[WT_M];
    const int t = threadIdx.x;
    {
        const float4* src = (const float4*)wt;
        float4* dst = (float4*)sW;
        for (int i = t; i < WT_M / 8; i += 512) dst[i] = src[i];
    }
    __syncthreads();
    const int lane = t & 63;
    const int w = t >> 6;  // 0..7
    const int rl = lane & 15;
    const int q = lane >> 4;
    const int rbase = blockIdx.x * 256 + w * 32;

    short8 af[2][4], al[2][4];
#pragma unroll
    for (int ri = 0; ri < 2; ++ri) {
        int row = min(rbase + ri * 16 + rl, nrows - 1);
#pragma unroll
        for (int kc = 0; kc < 4; ++kc) {
            if (AMODE == 2) {
                const float* ap = (const float*)Ap + (size_t)row * 128 + kc * 32 + q * 8;
                float4 f0 = *(const float4*)ap;
                float4 f1 = *(const float4*)(ap + 4);
                float fv[8] = {f0.x, f0.y, f0.z, f0.w, f1.x, f1.y, f1.z, f1.w};
                short8 hi, lo;
#pragma unroll
                for (int i = 0; i < 8; ++i) {
                    u16 hv = f2bf(fv[i]);
                    hi[i] = (short)hv;
                    lo[i] = (short)f2bf(fv[i] - bf2f(hv));
                }
                af[ri][kc] = hi;
                al[ri][kc] = lo;
            } else {
                af[ri][kc] = *(const short8*)((const u16*)Ap + (size_t)row * 128 + kc * 32 + q * 8);
                if (AMODE == 1)
                    al[ri][kc] = *(const short8*)((const u16*)Ap2 + (size_t)row * 128 + kc * 32 + q * 8);
            }
        }
    }

#pragma unroll
    for (int ct = 0; ct < 8; ++ct) {
        f32x4 acc0 = {0.f, 0.f, 0.f, 0.f};
        f32x4 acc1 = {0.f, 0.f, 0.f, 0.f};
#pragma unroll
        for (int kc = 0; kc < 4; ++kc) {
            short8 bf = *(const short8*)&sW[(ct * 16 + rl) * WT_S + kc * 32 + q * 8];
            if (AMODE != 0) {
                acc0 = __builtin_amdgcn_mfma_f32_16x16x32_bf16(al[0][kc], bf, acc0, 0, 0, 0);
                acc1 = __builtin_amdgcn_mfma_f32_16x16x32_bf16(al[1][kc], bf, acc1, 0, 0, 0);
            }
            acc0 = __builtin_amdgcn_mfma_f32_16x16x32_bf16(af[0][kc], bf, acc0, 0, 0, 0);
            acc1 = __builtin_amdgcn_mfma_f32_16x16x32_bf16(af[1][kc], bf, acc1, 0, 0, 0);
        }
        const int col = ct * 16 + rl;
        const float bs = bias[col];
        const float g = (EPI == 2) ? gg[col] : 0.f;
        const float be = (EPI == 2) ? bb[col] : 0.f;
#pragma unroll
        for (int half = 0; half < 2; ++half) {
            const f32x4& ac = half ? acc1 : acc0;
#pragma unroll
            for (int i = 0; i < 4; ++i) {
                int r = rbase + half * 16 + q * 4 + i;
                if (r < nrows) {
                    float v = ac[i] + bs;
                    if (EPI >= 1) v = v > 0.f ? v : 0.2f * v;
                    if (EPI == 2) v = g * v * BNS + be;
                    if (OMODE == 0)
                        outp[(size_t)r * 128 + col] = f2bf(v);
                    else
                        outp[((size_t)(col >> 5) * NN + r) * 32 + (col & 31)] = f2bf(v);
                }
            }
        }
    }
}

// ---------------- fused pool(sliced hbT) + vn MLP; writes vn + sliced bf16 mirror ----------------
__global__ __launch_bounds__(256) void k_vnup(
    const u16* __restrict__ hbT, const int* __restrict__ bstart,
    const float* __restrict__ counts, const float* __restrict__ W1,
    const float* __restrict__ b1, const float* __restrict__ W2,
    const float* __restrict__ b2, float* __restrict__ vn, u16* __restrict__ vnbT) {
    __shared__ float4 red[8][32];
    __shared__ float sP[128], sT[128], sH[2][128];
    const int b = blockIdx.x;
    const int t = threadIdx.x;
    const int s = bstart[b], e = bstart[b + 1];
    const int g = t >> 5, q = t & 31;
    const uint2* h2 = (const uint2*)hbT;
    const size_t fbase = (size_t)(q >> 3) * NN * 8;  // uint2 units
    const int fo = q & 7;
    float4 a = make_float4(0.f, 0.f, 0.f, 0.f);
    for (int r = s + g; r < e; r += 8) {
        uint2 v = h2[fbase + (size_t)r * 8 + fo];
        a.x += bf2f(v.x & 0xFFFFu); a.y += bf2f(v.x >> 16);
        a.z += bf2f(v.y & 0xFFFFu); a.w += bf2f(v.y >> 16);
    }
    red[g][q] = a;
    __syncthreads();
    if (g == 0) {
#pragma unroll
        for (int g2 = 1; g2 < 8; ++g2) {
            float4 v = red[g2][q];
            a.x += v.x; a.y += v.y; a.z += v.z; a.w += v.w;
        }
        float inv = 1.f / fmaxf(counts[b], 1.f);
        sP[q * 4 + 0] = a.x * inv;
        sP[q * 4 + 1] = a.y * inv;
        sP[q * 4 + 2] = a.z * inv;
        sP[q * 4 + 3] = a.w * inv;
    }
    __syncthreads();
    {
        const int c = t & 127, hf = t >> 7;
        float acc = 0.f;
        const float* Wp = W1 + (size_t)(hf * 64) * 128 + c;
#pragma unroll 8
        for (int k = 0; k < 64; ++k) acc += sP[hf * 64 + k] * Wp[(size_t)k * 128];
        sH[hf][c] = acc;
    }
    __syncthreads();
    if (t < 128) {
        float v = sH[0][t] + sH[1][t] + b1[t];
        sT[t] = v > 0.f ? v : 0.2f * v;
    }
    __syncthreads();
    {
        const int c = t & 127, hf = t >> 7;
        float acc = 0.f;
        const float* Wp = W2 + (size_t)(hf * 64) * 128 + c;
#pragma unroll 8
        for (int k = 0; k < 64; ++k) acc += sT[hf * 64 + k] * Wp[(size_t)k * 128];
        sH[hf][c] = acc;
    }
    __syncthreads();
    if (t < 128) {
        float nv = vn[(size_t)b * 128 + t] + sH[0][t] + sH[1][t] + b2[t];
        vn[(size_t)b * 128 + t] = nv;
        vnbT[((size_t)(t >> 5) * NB + b) * 32 + (t & 31)] = f2bf(nv);
    }
}

// ---------------- final: pool(sliced hbT) + BN + fc  (4 batches per block) ----------------
__global__ __launch_bounds__(256) void k_final(
    const u16* __restrict__ hbT, const int* __restrict__ bstart,
    const float* __restrict__ g, const float* __restrict__ bB,
    const float* __restrict__ fcW, const float* __restrict__ fcb,
    float* __restrict__ out) {
    __shared__ float sP[4][128];
    __shared__ float4 red[4][2][32];
    const int t = threadIdx.x;
    const int seg = t >> 6, gq = t & 63, rg = gq >> 5, q = gq & 31;
    const int b = blockIdx.x * 4 + seg;
    const int s = bstart[b], e = bstart[b + 1];
    const uint2* h2 = (const uint2*)hbT;
    const size_t fbase = (size_t)(q >> 3) * NN * 8;
    const int fo = q & 7;
    float4 a = make_float4(0.f, 0.f, 0.f, 0.f);
    for (int r = s + rg; r < e; r += 2) {
        uint2 v = h2[fbase + (size_t)r * 8 + fo];
        a.x += bf2f(v.x & 0xFFFFu); a.y += bf2f(v.x >> 16);
        a.z += bf2f(v.y & 0xFFFFu); a.w += bf2f(v.y >> 16);
    }
    red[seg][rg][q] = a;
    __syncthreads();
    if (rg == 0) {
        float4 v = red[seg][1][q];
        a.x += v.x; a.y += v.y; a.z += v.z; a.w += v.w;
        float av[4] = {a.x, a.y, a.z, a.w};
#pragma unroll
        for (int i = 0; i < 4; ++i) {
            int c = q * 4 + i;
            sP[seg][c] = g[c] * av[i] * BNS + bB[c];
        }
    }
    __syncthreads();
    const int o = t & 63;
    float acc = fcb[o];
    const float* wrow = fcW + o * 128;
    const float* prow = sP[seg];
    for (int k = 0; k < 128; ++k) acc += prow[k] * wrow[k];
    out[(size_t)b * 64 + o] = acc;
}

extern "C" void kernel_launch(void* const* d_in, const int* in_sizes, int n_in,
                              void* d_out, int out_size, void* d_ws, size_t ws_size,
                              hipStream_t stream) {
    const float* x       = (const float*)d_in[0];
    const int*   ei      = (const int*)d_in[1];
    const int*   batch   = (const int*)d_in[2];
    const float* node_W  = (const float*)d_in[3];
    const float* node_b  = (const float*)d_in[4];
    const float* conv_W1 = (const float*)d_in[5];
    const float* conv_b1 = (const float*)d_in[6];
    const float* conv_g  = (const float*)d_in[7];
    const float* conv_bt = (const float*)d_in[8];
    const float* conv_W2 = (const float*)d_in[9];
    const float* conv_b2 = (const float*)d_in[10];
    const float* vn_emb  = (const float*)d_in[11];
    const float* vn_W1   = (const float*)d_in[12];
    const float* vn_b1   = (const float*)d_in[13];
    const float* vn_W2   = (const float*)d_in[14];
    const float* vn_b2   = (const float*)d_in[15];
    const float* bn_g    = (const float*)d_in[16];
    const float* bn_b    = (const float*)d_in[17];
    const float* fc_W    = (const float*)d_in[18];
    const float* fc_b    = (const float*)d_in[19];
    float* out = (float*)d_out;

    char* ws = (char*)d_ws;
    u16* hbT   = (u16*)ws;                        // NN*128 bf16, feature-sliced
    u16* aggh  = hbT + (size_t)NN * 128;          // NN*128 bf16 node-major (agg hi / z)
    u16* agglo = aggh + (size_t)NN * 128;         // NN*128 bf16 node-major (agg lo)
    u16* wt    = agglo + (size_t)NN * 128;        // 7*WT_M bf16
    u32* nbr   = (u32*)(wt + 7 * WT_M);           // NN*DCAP u32 (padded CSR, src|batch<<16)
    float* vn  = (float*)(nbr + (size_t)NN * DCAP);  // NB*128 f32
    u16* vnbT  = (u16*)(vn + NB * 128);           // NB*128 bf16, feature-sliced
    float* counts = (float*)(vnbT + NB * 128);    // NB
    int* bstart = (int*)(counts + NB);            // NB+1
    int* deg    = bstart + NB + 1;                // NN  <- zeroed

    hipMemsetAsync(deg, 0, NN * sizeof(int), stream);
    k_prep<<<704, 256, 0, stream>>>(node_W, conv_W1, conv_W2, wt,
                                    vn_emb, vn, vnbT, batch, bstart, counts);
    k_pcsr<<<(NE + 255) / 256, 256, 0, stream>>>(ei, batch, deg, nbr);

    const int GG = (NN + 255) / 256;        // 196 gemm blocks
    const int GGA = 8 * ((HNN + 31) / 32);  // 8 slices x 782 = 6256 gather blocks

    // node encoder: hbT = sliced bf16(x @ node_W + node_b)
    k_gemm<0, 2, 1><<<GG, 512, 0, stream>>>(
        x, nullptr, wt, node_b, nullptr, nullptr, hbT, NN);

    for (int l = 0; l < 3; ++l) {
        // agg (vn folded in) -> hi/lo split, node-major
        k_gather<<<GGA, 256, 0, stream>>>(deg, nbr, hbT, vnbT, batch, aggh, agglo);
        // z = bn(leaky(agg @ W1 + b1)) -> bf16 node-major, in-place into aggh
        k_gemm<2, 1, 0><<<GG, 512, 0, stream>>>(
            aggh, agglo, wt + (size_t)(1 + l) * WT_M, conv_b1 + l * 128,
            conv_g + l * 128, conv_bt + l * 128, aggh, NN);
        // hbT = sliced bf16(leaky(z @ W2 + b2))
        k_gemm<1, 0, 1><<<GG, 512, 0, stream>>>(
            aggh, nullptr, wt + (size_t)(4 + l) * WT_M, conv_b2 + l * 128,
            nullptr, nullptr, hbT, NN);
        // vn += mlp(pool(hbT)/denom)   (dead for l=2 -> skip)
        if (l < 2)
            k_vnup<<<NB, 256, 0, stream>>>(hbT, bstart, counts, vn_W1 + l * 16384,
                                           vn_b1 + l * 128, vn_W2 + l * 16384,
                                           vn_b2 + l * 128, vn, vnbT);
    }

    k_final<<<NB / 4, 256, 0, stream>>>(hbT, bstart, bn_g, bn_b, fc_W, fc_b, out);
}